// Round 2
// 126.266 us; speedup vs baseline: 1.0236x; 1.0236x over previous
//
#include <hip/hip_runtime.h>
#include <hip/hip_bf16.h>
#include <math.h>

#define BATCH 8
#define SEQ 2048
#define EMBED 1024
#define HEAD 64
#define NROWS (BATCH*SEQ)   // 16384

typedef short bf16x8 __attribute__((ext_vector_type(8)));
typedef short bf16x4 __attribute__((ext_vector_type(4)));
typedef float f32x4  __attribute__((ext_vector_type(4)));

__device__ inline short f2bf(float f) {
    __hip_bfloat16 h = __float2bfloat16(f);
    return *(short*)&h;
}
__device__ inline float bf2f(short s) {
    __hip_bfloat16 h = *(__hip_bfloat16*)&s;
    return __bfloat162float(h);
}

// Dense triangular slots, 64-row qt tiles, 4-chunk segments:
// slots(qt) = (qt>>2)+1; triOff(qt) = 2g(g+1)+(qt&3)(g+1), g=qt>>2. 144/batch.
#define NSLOT 144
__device__ __host__ inline int triOff(int qt) {
    int g = qt >> 2;
    return 2 * g * (g + 1) + (qt & 3) * (g + 1);
}

// ---------------------------------------------------------------------------
// Kernel 0: W -> bf16 B-fragment order for 16x16x32 MFMA.
// ---------------------------------------------------------------------------
__global__ __launch_bounds__(256) void prep_w(
    const float* __restrict__ Wq, const float* __restrict__ Wk,
    const float* __restrict__ Wv, short* __restrict__ wt)
{
    int g    = blockIdx.x * 256 + threadIdx.x;   // 24576 total
    int lane = g & 63;
    int frag = g >> 6;           // ct*32 + k32
    int k32  = frag & 31;
    int ct   = frag >> 5;        // 0..11
    int col  = ct * 16 + (lane & 15);
    int mm   = col >> 6, cc = col & 63;
    const float* W = (mm == 0) ? Wq : ((mm == 1) ? Wk : Wv);
    int kb = k32 * 32 + (lane >> 4) * 8;
    bf16x8 o;
#pragma unroll
    for (int j = 0; j < 8; j++)
        o[j] = f2bf(W[(size_t)(kb + j) * HEAD + cc]);
    *(bf16x8*)&wt[(size_t)g * 8] = o;
}

// ---------------------------------------------------------------------------
// Kernel 1: QKV projection (single-stage slab, proven R7). V written
// TRANSPOSED per batch: vt[b][h][t].
// ---------------------------------------------------------------------------
__global__ __launch_bounds__(512, 4) void proj_kernel(
    const float* __restrict__ x, const short* __restrict__ wt,
    short* __restrict__ q, short* __restrict__ k, short* __restrict__ vt)
{
    __shared__ short xs[32][1024];   // 64 KB, XOR-swizzled k8 blocks
    float* psum = (float*)&xs[0][0]; // reuse after compute barrier

    const int tid  = threadIdx.x;
    const int wave = tid >> 6, lane = tid & 63;
    const int m16  = lane & 15, quad = lane >> 4;
    const int cg   = wave & 3;
    const int kh   = wave >> 2;
    const int r0   = blockIdx.x * 32;

    {
        const int row  = tid >> 4;
        const int col4 = tid & 15;
        const float* xr = x + (size_t)(r0 + row) * EMBED;
#pragma unroll
        for (int h = 0; h < 2; h++) {
            float4 f[8];
#pragma unroll
            for (int i = 0; i < 8; i++)
                f[i] = *(const float4*)&xr[(h * 8 + i) * 64 + col4 * 4];
#pragma unroll
            for (int i = 0; i < 8; i++) {
                int c  = (h * 8 + i) * 64 + col4 * 4;
                int k8 = c >> 3, rem = c & 7;
                int cs = ((k8 ^ (row & 7)) << 3) + rem;
                bf16x4 bv;
                bv[0] = f2bf(f[i].x); bv[1] = f2bf(f[i].y);
                bv[2] = f2bf(f[i].z); bv[3] = f2bf(f[i].w);
                *(bf16x4*)&xs[row][cs] = bv;
            }
        }
    }
    __syncthreads();

    f32x4 acc[2][3];
#pragma unroll
    for (int mt = 0; mt < 2; mt++)
#pragma unroll
        for (int j = 0; j < 3; j++) acc[mt][j] = (f32x4){0.f, 0.f, 0.f, 0.f};

#pragma unroll 4
    for (int s = 0; s < 16; s++) {
        int k32  = kh * 16 + s;
        int ksw  = ((k32 * 4 + quad) ^ (m16 & 7)) << 3;
        bf16x8 a0 = *(const bf16x8*)&xs[m16][ksw];
        bf16x8 a1 = *(const bf16x8*)&xs[16 + m16][ksw];
#pragma unroll
        for (int j = 0; j < 3; j++) {
            int ct = cg * 3 + j;
            bf16x8 bb = *(const bf16x8*)&wt[(size_t)((ct * 32 + k32) * 64 + lane) * 8];
            acc[0][j] = __builtin_amdgcn_mfma_f32_16x16x32_bf16(a0, bb, acc[0][j], 0, 0, 0);
            acc[1][j] = __builtin_amdgcn_mfma_f32_16x16x32_bf16(a1, bb, acc[1][j], 0, 0, 0);
        }
    }

    __syncthreads();
    if (kh == 1) {
        float* p = psum + ((size_t)(cg * 64 + lane) * 24);
#pragma unroll
        for (int mt = 0; mt < 2; mt++)
#pragma unroll
            for (int j = 0; j < 3; j++)
                *(f32x4*)&p[(mt * 3 + j) * 4] = acc[mt][j];
    }
    __syncthreads();
    if (kh == 0) {
        const float* p = psum + ((size_t)(cg * 64 + lane) * 24);
        const int bb = r0 >> 11;
        const int tb = r0 & 2047;
#pragma unroll
        for (int mt = 0; mt < 2; mt++)
#pragma unroll
            for (int j = 0; j < 3; j++) {
                f32x4 o = acc[mt][j] + *(const f32x4*)&p[(mt * 3 + j) * 4];
                int gcol = (cg * 3 + j) * 16 + m16;
                int mm = gcol >> 6, cc = gcol & 63;
                if (mm < 2) {
                    short* op = (mm == 0) ? q : k;
#pragma unroll
                    for (int reg = 0; reg < 4; reg++) {
                        int row = r0 + mt * 16 + quad * 4 + reg;
                        op[(size_t)row * HEAD + cc] = f2bf(o[reg]);
                    }
                } else {
                    bf16x4 pk;
                    pk[0] = f2bf(o[0]); pk[1] = f2bf(o[1]);
                    pk[2] = f2bf(o[2]); pk[3] = f2bf(o[3]);
                    int t = tb + mt * 16 + quad * 4;
                    *(bf16x4*)&vt[(((size_t)bb * 64 + cc) << 11) + t] = pk;
                }
            }
    }
}

// ---------------------------------------------------------------------------
// Kernel 2: split-K flash attention, R6/R7-proven 2-barrier skeleton.
// Operand-swapped QK^T (mfma(K,Q) -> S^T): q-row is lane-local (q = m16).
// Softmax P values pack into 4x ds_write_b64 (was 16x ds_write_b16), lsum is
// a per-lane scalar with a 2-shuffle epilogue reduction (was 16 shuffles),
// and the PV A-frag read from psh is byte-identical to the proven layout.
// ---------------------------------------------------------------------------
__global__ __launch_bounds__(256, 5) void attn_kernel(
    const short* __restrict__ qg, const short* __restrict__ kg,
    const short* __restrict__ vtg,
    short* __restrict__ pO, float* __restrict__ pl)
{
    __shared__ short ksh[64][72];      // [t][h]   9216 B
    __shared__ short vsh[64][72];      // [h][t]   9216 B (from vt, natural)
    __shared__ short psh[4][16][72];   // [wave][q=m16][t] 9216 B, wave-private

    const int qt  = blockIdx.x;        // 0..31
    const int seg = blockIdx.y;        // 0..7
    const int b   = blockIdx.z;
    const int c0  = seg * 4;
    const int c1  = min(seg * 4 + 4, qt + 1);
    if (c0 >= c1) return;

    const int tid  = threadIdx.x;
    const int wave = tid >> 6, lane = tid & 63;
    const int m16  = lane & 15, quad = lane >> 4;
    const float scale = 0.03125f;      // 1024^-0.5

    const short* qb  = qg  + (size_t)b * SEQ * HEAD;
    const short* kb  = kg  + (size_t)b * SEQ * HEAD;
    const short* vtb = vtg + (size_t)b * HEAD * SEQ;

    bf16x8 a_q0, a_q1;
    {
        const int qrow = qt * 64 + wave * 16 + m16;
        a_q0 = *(const bf16x8*)&qb[(size_t)qrow * HEAD + quad * 8];
        a_q1 = *(const bf16x8*)&qb[(size_t)qrow * HEAD + 32 + quad * 8];
    }
    const int myrow = qt * 64 + wave * 16 + m16;   // lane-local q row

    f32x4 o_acc[4];
#pragma unroll
    for (int i = 0; i < 4; i++) o_acc[i] = (f32x4){0.f, 0.f, 0.f, 0.f};
    float lsum = 0.f;

    // staging: thread owns two 16B segments of K and two of V (rows r, r+32)
    const int srow = tid >> 3;         // 0..31
    const int sc8  = (tid & 7) * 8;    // 0..56

    bf16x8 kr0 = *(const bf16x8*)&kb[(size_t)(c0 * 64 + srow) * HEAD + sc8];
    bf16x8 kr1 = *(const bf16x8*)&kb[(size_t)(c0 * 64 + 32 + srow) * HEAD + sc8];
    bf16x8 vr0 = *(const bf16x8*)&vtb[((size_t)srow << 11) + c0 * 64 + sc8];
    bf16x8 vr1 = *(const bf16x8*)&vtb[((size_t)(srow + 32) << 11) + c0 * 64 + sc8];

    for (int c = c0; c < c1; c++) {
        const int t0 = c * 64;
        __syncthreads();               // barrier A: prev-iter LDS readers done
        *(bf16x8*)&ksh[srow][sc8]      = kr0;
        *(bf16x8*)&ksh[srow + 32][sc8] = kr1;
        *(bf16x8*)&vsh[srow][sc8]      = vr0;
        *(bf16x8*)&vsh[srow + 32][sc8] = vr1;
        __syncthreads();               // barrier B: stores visible
        if (c + 1 < c1) {              // prefetch next chunk (overlaps compute)
            const int tn = (c + 1) * 64;
            kr0 = *(const bf16x8*)&kb[(size_t)(tn + srow) * HEAD + sc8];
            kr1 = *(const bf16x8*)&kb[(size_t)(tn + 32 + srow) * HEAD + sc8];
            vr0 = *(const bf16x8*)&vtb[((size_t)srow << 11) + tn + sc8];
            vr1 = *(const bf16x8*)&vtb[((size_t)(srow + 32) << 11) + tn + sc8];
        }

        // ---- QK^T from LDS, swapped operands: C = S^T, col(lane&15) = q ----
        // s_t[nt][r] = S[q = myrow][t = t0 + nt*16 + quad*4 + r]
        f32x4 s_t[4];
#pragma unroll
        for (int nt = 0; nt < 4; nt++) {
            bf16x8 ak0 = *(const bf16x8*)&ksh[nt * 16 + m16][quad * 8];
            bf16x8 ak1 = *(const bf16x8*)&ksh[nt * 16 + m16][32 + quad * 8];
            f32x4 acc = (f32x4){0.f, 0.f, 0.f, 0.f};
            acc = __builtin_amdgcn_mfma_f32_16x16x32_bf16(ak0, a_q0, acc, 0, 0, 0);
            acc = __builtin_amdgcn_mfma_f32_16x16x32_bf16(ak1, a_q1, acc, 0, 0, 0);
            s_t[nt] = acc;
        }

        // ---- no-max softmax; mask only on the diagonal chunk ----
        // lane owns row q = myrow; its 16 t-slots are nt*16 + quad*4 + r.
        if (c == qt) {
#pragma unroll
            for (int nt = 0; nt < 4; nt++) {
                bf16x4 pk;
#pragma unroll
                for (int r = 0; r < 4; r++) {
                    int tt = t0 + nt * 16 + quad * 4 + r;
                    float p = (tt <= myrow) ? __expf(s_t[nt][r] * scale) : 0.f;
                    lsum += p;
                    pk[r] = f2bf(p);
                }
                *(bf16x4*)&psh[wave][m16][nt * 16 + quad * 4] = pk;
            }
        } else {
#pragma unroll
            for (int nt = 0; nt < 4; nt++) {
                bf16x4 pk;
#pragma unroll
                for (int r = 0; r < 4; r++) {
                    float p = __expf(s_t[nt][r] * scale);
                    lsum += p;
                    pk[r] = f2bf(p);
                }
                *(bf16x4*)&psh[wave][m16][nt * 16 + quad * 4] = pk;
            }
        }
        // psh wave-private: in-wave LDS ordering suffices, no barrier.

        // ---- PV: A-frag natural from psh[q=m16][t]; B-frags from vsh[h][t] ----
#pragma unroll
        for (int ss = 0; ss < 2; ss++) {
            bf16x8 a_p = *(const bf16x8*)&psh[wave][m16][ss * 32 + quad * 8];
#pragma unroll
            for (int ht = 0; ht < 4; ht++) {
                bf16x8 b_v = *(const bf16x8*)&vsh[ht * 16 + m16][ss * 32 + quad * 8];
                o_acc[ht] = __builtin_amdgcn_mfma_f32_16x16x32_bf16(a_p, b_v, o_acc[ht], 0, 0, 0);
            }
        }
    }

    // ---- epilogue: row-sum of l across the 4 quads, write partials ----
    lsum += __shfl_xor(lsum, 16, 64);
    lsum += __shfl_xor(lsum, 32, 64);
    const size_t slot  = (size_t)b * NSLOT + triOff(qt) + seg;
    const size_t pbase = slot * 64;
#pragma unroll
    for (int ht = 0; ht < 4; ht++) {
#pragma unroll
        for (int r = 0; r < 4; r++) {
            int rowt = wave * 16 + quad * 4 + r;
            pO[(pbase + rowt) * 64 + ht * 16 + m16] = f2bf(o_acc[ht][r]);
        }
    }
    if (quad == 0) {
        pl[pbase + wave * 16 + m16] = lsum;
    }
}

// ---------------------------------------------------------------------------
// Kernel 3: combine split-K partials: out = (sum_s O_s) / (sum_s l_s).
// Vectorized: 16B bf16x8 loads, 2x float4 stores, half the threads.
// ---------------------------------------------------------------------------
__global__ __launch_bounds__(256) void combine_kernel(
    const short* __restrict__ pO, const float* __restrict__ pl,
    float* __restrict__ out)
{
    int g   = blockIdx.x * 256 + threadIdx.x;   // 131072
    int h8  = (g & 7) * 8;
    int row = (g >> 3) & 2047;
    int b   = g >> 14;
    int qt  = row >> 6, lr = row & 63;
    int ns  = (qt >> 2) + 1;
    size_t base = (size_t)b * NSLOT + triOff(qt);
    float O[8] = {0.f, 0.f, 0.f, 0.f, 0.f, 0.f, 0.f, 0.f};
    float L = 0.f;
    for (int s = 0; s < ns; s++) {
        bf16x8 ov = *(const bf16x8*)&pO[((base + s) * 64 + lr) * 64 + h8];
#pragma unroll
        for (int j = 0; j < 8; j++) O[j] += bf2f(ov[j]);
        L += pl[(base + s) * 64 + lr];
    }
    float inv = 1.f / L;
    float4 o0 = {O[0] * inv, O[1] * inv, O[2] * inv, O[3] * inv};
    float4 o1 = {O[4] * inv, O[5] * inv, O[6] * inv, O[7] * inv};
    *(float4*)&out[(size_t)g * 8]     = o0;
    *(float4*)&out[(size_t)g * 8 + 4] = o1;
}

// ---------------------------------------------------------------------------
extern "C" void kernel_launch(void* const* d_in, const int* in_sizes, int n_in,
                              void* d_out, int out_size, void* d_ws, size_t ws_size,
                              hipStream_t stream) {
    const float* x  = (const float*)d_in[0];
    const float* Wq = (const float*)d_in[1];
    const float* Wk = (const float*)d_in[2];
    const float* Wv = (const float*)d_in[3];
    float* out = (float*)d_out;

    short* q  = (short*)d_ws;                       // 1,048,576
    short* k  = q + (size_t)NROWS * HEAD;           // 1,048,576
    short* vt = k + (size_t)NROWS * HEAD;           // 1,048,576 (transposed)
    short* wt = vt + (size_t)NROWS * HEAD;          //   196,608
    short* pO = wt + 196608;                        // 8*144*64*64 = 4,718,592
    float* pl = (float*)(pO + (size_t)BATCH * NSLOT * 64 * 64);  // 73,728

    prep_w<<<96, 256, 0, stream>>>(Wq, Wk, Wv, wt);
    proj_kernel<<<512, 512, 0, stream>>>(x, wt, q, k, vt);
    attn_kernel<<<dim3(32, 8, 8), 256, 0, stream>>>(q, k, vt, pO, pl);
    combine_kernel<<<512, 256, 0, stream>>>(pO, pl, out);
}